// Round 12
// baseline (141.579 us; speedup 1.0000x reference)
//
#include <hip/hip_runtime.h>

// Problem constants
#define NB 4
#define SEQ 2048
#define CD 64            // head dim == model dim
#define NHEAD 8
#define BHN (NB * NHEAD) // 32
#define ROWS (NB * SEQ)  // 8192
#define HC 512           // H*CD

#define QSCALE 0.18033688011112042f   // 0.125 * log2(e)
#define SHIFT  23.083120654223414f    // 16 * log2(e)

typedef float f32x4 __attribute__((ext_vector_type(4)));
typedef short s16x8 __attribute__((ext_vector_type(8)));
typedef unsigned short u16;
typedef unsigned int u32;

__device__ __forceinline__ u16 f2bf(float x) {
  union { float f; unsigned u; } v; v.f = x;
  unsigned r = v.u + 0x7FFFu + ((v.u >> 16) & 1u);
  return (u16)(r >> 16);
}

__device__ __forceinline__ float fast_exp2(float x) {
#if __has_builtin(__builtin_amdgcn_exp2f)
  return __builtin_amdgcn_exp2f(x);
#else
  return exp2f(x);
#endif
}

__device__ __forceinline__ u32 bitsf(float x) {
  union { float f; u32 u; } v; v.f = x; return v.u;
}

// pack hi16 of two f32 (truncating bf16 convert): {lo:=a_hi16, hi:=b_hi16}
__device__ __forceinline__ u32 pack_trunc(float a, float b) {
#if __has_builtin(__builtin_amdgcn_perm)
  return __builtin_amdgcn_perm(bitsf(b), bitsf(a), 0x07060302u);
#else
  return (bitsf(a) >> 16) | (bitsf(b) & 0xFFFF0000u);
#endif
}

__device__ __forceinline__ u32 pack_rne(float a, float b) {
  return (u32)f2bf(a) | ((u32)f2bf(b) << 16);
}

__device__ __forceinline__ f32x4 mfma_bf16(s16x8 a, s16x8 b, f32x4 c) {
  return __builtin_amdgcn_mfma_f32_16x16x32_bf16(a, b, c, 0, 0, 0);
}

// relaxed agent-scope f32 atomic add -> global_atomic_add_f32
__device__ __forceinline__ void atomAddF32(float* p, float v) {
  __hip_atomic_fetch_add(p, v, __ATOMIC_RELAXED, __HIP_MEMORY_SCOPE_AGENT);
}

// async global -> LDS DMA, 16B per lane; LDS dest = uniform base + lane*16
typedef __attribute__((address_space(1))) const u32* gp1;
typedef __attribute__((address_space(3))) u32* lp3;
__device__ __forceinline__ void dma16(const void* g, void* l) {
  __builtin_amdgcn_global_load_lds((gp1)g, (lp3)l, 16, 0, 0);
}

// ---------------------------------------------------------------------------
// Kernel 1: fused prep + qkv (R10/R11-validated).
// blockIdx.x == 128 (8 blocks): pack Wproj into MFMA B-fragments WpF.
// blockIdx.x < 128: qkv via MFMA; Wqkv slice transposed inline into LDS.
// Q (scaled) & K written [B,H,N,64] via operand-swapped MFMA (8B stores);
// V tiled-transposed Vt[bh][n>>5][c][n&31]. grid (129, 8), block 256.
// ---------------------------------------------------------------------------
__global__ void __launch_bounds__(256) qkv_kernel(
    const float* __restrict__ x, const float* __restrict__ Wqkv,
    const float* __restrict__ Wproj, u16* __restrict__ Q, u16* __restrict__ K,
    u16* __restrict__ Vt, u16* __restrict__ WpF) {
  const int t = threadIdx.x;

  if (blockIdx.x == 128) {
    // prep path: WpF[f*512 + lane*8 + j] = Wproj[k*64+col], f = kcg*4+nb
    for (int i = blockIdx.y * 256 + t; i < 64 * 512; i += 2048) {
      const int f = i >> 9, ln = (i >> 3) & 63, j = i & 7;
      const int col = (f & 3) * 16 + (ln & 15);
      const int k = (f >> 2) * 32 + (ln >> 4) * 8 + j;
      WpF[i] = f2bf(Wproj[k * 64 + col]);
    }
    return;
  }

  __shared__ __align__(16) u16 xs[64 * 72];    // [row][c] stride 72
  __shared__ __align__(16) u16 wts[192 * 72];  // [n][k]  stride 72

  const int w = t >> 6, lane = t & 63, quad = lane >> 4, c16 = lane & 15;
  const int rb = blockIdx.x * 64;
  const int c0 = blockIdx.y * 192;

  // stage x tile (64 rows x 64 c), f32 -> bf16, coalesced
  {
    const int row = t >> 2, cc0 = (t & 3) * 16;
    const float* xp = x + (size_t)(rb + row) * CD + cc0;
    union { u16 u[16]; int4 v[2]; } bx;
#pragma unroll
    for (int j = 0; j < 16; j += 4) {
      float4 xv = *(const float4*)(xp + j);
      bx.u[j] = f2bf(xv.x); bx.u[j + 1] = f2bf(xv.y);
      bx.u[j + 2] = f2bf(xv.z); bx.u[j + 3] = f2bf(xv.w);
    }
    *(int4*)&xs[row * 72 + cc0] = bx.v[0];
    *(int4*)&xs[row * 72 + cc0 + 8] = bx.v[1];
  }
  // stage Wqkv slice [64 k][192 n] TRANSPOSED into wts[n][k]
#pragma unroll
  for (int p = 0; p < 12; ++p) {
    const int idx = p * 256 + t;               // 0..3071 = 16 k4 x 192 n
    const int n = idx % 192, k4 = (idx / 192) * 4;
    const float* wp = Wqkv + (size_t)k4 * 1536 + c0 + n;
    const float w0 = wp[0], w1 = wp[1536], w2 = wp[3072], w3 = wp[4608];
    uint2 pk;
    pk.x = pack_rne(w0, w1);
    pk.y = pack_rne(w2, w3);
    *(uint2*)&wts[n * 72 + k4] = pk;
  }
  __syncthreads();

  s16x8 af[2];
#pragma unroll
  for (int kc = 0; kc < 2; ++kc)
    af[kc] = *(const s16x8*)&xs[(w * 16 + c16) * 72 + kc * 32 + quad * 8];

  const int rw = rb + w * 16;
  const int b = rw >> 11;
  const int nn0 = rw & (SEQ - 1);

#pragma unroll
  for (int nb = 0; nb < 12; ++nb) {
    const int cb = c0 + nb * 16;           // wave-uniform column base
    const int three = cb >> 9;
    const int h = (cb >> 6) & 7;
    const int ccb = cb & 63;
    const int bhv = b * NHEAD + h;
    s16x8 bf_[2];
#pragma unroll
    for (int kc = 0; kc < 2; ++kc)
      bf_[kc] = *(const s16x8*)&wts[(nb * 16 + c16) * 72 + kc * 32 + quad * 8];

    if (three == 2) {
      // V: C[row][col], lane col=c16 fixed, 4 consecutive n packed
      f32x4 acc = (f32x4){0.f, 0.f, 0.f, 0.f};
#pragma unroll
      for (int kc = 0; kc < 2; ++kc) acc = mfma_bf16(af[kc], bf_[kc], acc);
      uint2 pk;
      pk.x = pack_rne(acc[0], acc[1]);
      pk.y = pack_rne(acc[2], acc[3]);
      const size_t off = (size_t)bhv * (SEQ * CD) + (size_t)(nn0 >> 5) * 2048 +
                         (size_t)(ccb + c16) * 32 + (rw & 31) + quad * 4;
      *(uint2*)(Vt + off) = pk;
    } else {
      // Q/K: swapped operands -> C[col][row], lane row=c16, 4 cols packed
      f32x4 acc = (f32x4){0.f, 0.f, 0.f, 0.f};
#pragma unroll
      for (int kc = 0; kc < 2; ++kc) acc = mfma_bf16(bf_[kc], af[kc], acc);
      u16* dstp = (three == 0) ? Q : K;
      const float scl = (three == 0) ? QSCALE : 1.0f;
      uint2 pk;
      pk.x = pack_rne(acc[0] * scl, acc[1] * scl);
      pk.y = pack_rne(acc[2] * scl, acc[3] * scl);
      *(uint2*)(dstp + ((size_t)bhv * SEQ + nn0 + c16) * CD + ccb + quad * 4) =
          pk;
    }
  }
}

// ---------------------------------------------------------------------------
// Kernel 2: FUSED flash attention + head-separable projection (atomics).
// Attn core = R11 (in-block K-split x2, barrier-free vmcnt K-loop,
// single-buffer staging, per-qb P slots, R5 XOR swizzle).
// Epilogue: symmetric combine (wave w combines q-half w), combined tile ->
// LDS bf16 A-layout, 16 MFMA/wave vs WpF frags (this head's K=64 slice),
// f32 atomic-add partials into out (bias added once by h==0 blocks).
// No grid sync needed: out[n] = sum over heads of O_h[n] @ Wp_h.
// grid (32, 32), block 128 (2 waves). out must be pre-zeroed.
// ---------------------------------------------------------------------------
__global__ void __launch_bounds__(128, 2) attnproj_kernel(
    const u16* __restrict__ Q, const u16* __restrict__ K,
    const u16* __restrict__ Vt, const u16* __restrict__ WpF,
    const float* __restrict__ bias, float* __restrict__ out) {
  // K-loop layout (u16): [w*4096]: K (2048) | V (2048)
  //                      [8192 + w*2560 + qb*640]: P slot (16 x stride 40)
  // Epilogue layout:     [0..8191] Xo f32[2][32][64]; [8192..8319] Lo f32[64];
  //                      [8320..12927] Ot bf16 [64][72]
  __shared__ __align__(16) u16 smem[13312];

  const int t = threadIdx.x;
  const int w = t >> 6, lane = t & 63, quad = lane >> 4, c16 = lane & 15;
  const int bh = blockIdx.y;
  const int q0 = blockIdx.x * 64;
  const int kt0 = w * (SEQ / 2);

  u16* KsW = smem + w * 4096;          // [2048]
  u16* VsW = smem + w * 4096 + 2048;   // [2048]
  u16* Pw  = smem + 8192 + w * 2560;   // 4 slots x [16*40]

  const u16* Qb = Q + (size_t)bh * SEQ * CD;
  const u16* Kb = K + (size_t)bh * SEQ * CD;
  const u16* Vb = Vt + (size_t)bh * SEQ * CD;  // tiled [n>>5][c][n&31]

  // Q B-operand fragments (same for both waves): B[k=c][n=q]
  s16x8 qfb[4][2];
#pragma unroll
  for (int qb = 0; qb < 4; ++qb)
#pragma unroll
    for (int cc = 0; cc < 2; ++cc)
      qfb[qb][cc] = *(const s16x8*)(Qb + (size_t)(q0 + qb * 16 + c16) * CD +
                                    cc * 32 + quad * 8);

  s16x8 onesf;
  {
    const short one = (c16 == 0) ? (short)0x3F80 : (short)0;
#pragma unroll
    for (int j = 0; j < 8; ++j) onesf[j] = one;
  }

  f32x4 o[4][4], osum[4];
#pragma unroll
  for (int qb = 0; qb < 4; ++qb) {
    osum[qb] = (f32x4){0.f, 0.f, 0.f, 0.f};
#pragma unroll
    for (int cb = 0; cb < 4; ++cb) o[qb][cb] = (f32x4){0.f, 0.f, 0.f, 0.f};
  }

  // staging lane constants (R5-verified XOR swizzle, 0 conflicts)
  const int krl = lane >> 3, kcl = (lane & 7) ^ ((lane >> 3) & 7);
  const int vrl = lane >> 2, vcl = (lane & 3) ^ ((lane >> 3) & 3);

  // fragment LDS offsets (swizzle-matched)
  int kOff[2][2], vOff[4];
#pragma unroll
  for (int kb = 0; kb < 2; ++kb)
#pragma unroll
    for (int cc = 0; cc < 2; ++cc)
      kOff[kb][cc] = (kb * 16 + c16) * 64 + (((cc * 4 + quad) ^ (c16 & 7)) * 8);
#pragma unroll
  for (int cb = 0; cb < 4; ++cb)
    vOff[cb] = (cb * 16 + c16) * 32 + ((quad ^ ((c16 >> 1) & 3)) * 8);

#define STAGE_TILE(kt_)                                                        \
  {                                                                            \
    const u16* ksrc = Kb + (size_t)(kt_) * CD;                                 \
    _Pragma("unroll") for (int d = 0; d < 4; ++d)                              \
        dma16(ksrc + (size_t)(d * 8 + krl) * CD + kcl * 8, KsW + d * 512);     \
    const u16* vsrc = Vb + (size_t)((kt_) >> 5) * 2048;                        \
    _Pragma("unroll") for (int d = 0; d < 4; ++d)                              \
        dma16(vsrc + (size_t)(d * 16 + vrl) * 32 + vcl * 8, VsW + d * 512);    \
  }

  STAGE_TILE(kt0)

  for (int it = 0; it < 32; ++it) {
    __builtin_amdgcn_s_waitcnt(0x0F70);  // vmcnt(0): current tile landed

    s16x8 kf[2][2], vf[4];
#pragma unroll
    for (int kb = 0; kb < 2; ++kb)
#pragma unroll
      for (int cc = 0; cc < 2; ++cc)
        kf[kb][cc] = *(const s16x8*)&KsW[kOff[kb][cc]];
#pragma unroll
    for (int cb = 0; cb < 4; ++cb)
      vf[cb] = *(const s16x8*)&VsW[vOff[cb]];

    __builtin_amdgcn_s_waitcnt(0xC07F);  // lgkmcnt(0): frags in regs, LDS free
    if (it + 1 < 32) STAGE_TILE(kt0 + (it + 1) * 32)

    // 4 independent qb chains (per-qb P slot -> no WAR serialization)
#pragma unroll
    for (int qb = 0; qb < 4; ++qb) {
      u16* Pq = Pw + qb * 640;
#pragma unroll
      for (int kb = 0; kb < 2; ++kb) {
        f32x4 s = (f32x4){-SHIFT, -SHIFT, -SHIFT, -SHIFT};
        s = mfma_bf16(kf[kb][0], qfb[qb][0], s);
        s = mfma_bf16(kf[kb][1], qfb[qb][1], s);
        uint2 pk;
        pk.x = pack_trunc(fast_exp2(s[0]), fast_exp2(s[1]));
        pk.y = pack_trunc(fast_exp2(s[2]), fast_exp2(s[3]));
        *(uint2*)&Pq[c16 * 40 + kb * 16 + quad * 4] = pk;
      }
      const s16x8 pf = *(const s16x8*)&Pq[c16 * 40 + quad * 8];
#pragma unroll
      for (int cb = 0; cb < 4; ++cb)
        o[qb][cb] = mfma_bf16(pf, vf[cb], o[qb][cb]);
      osum[qb] = mfma_bf16(pf, onesf, osum[qb]);
    }
  }
#undef STAGE_TILE

  // ---- symmetric combine: wave w combines q-half w (qb = 2w, 2w+1) ----
  float* Xo = (float*)smem;             // [half][32 q][64 c] f32 (16 KB)
  float* Lo = (float*)(smem + 8192);    // [half][32] f32
  u16*  Ot  = smem + 8320;              // [64 q][72 c] bf16

  __syncthreads();  // all compute done; staging + P + scratch dead
  // publish partial for the OTHER wave's half
#pragma unroll
  for (int j = 0; j < 2; ++j) {
    const int qb = (w ^ 1) * 2 + j;
#pragma unroll
    for (int cb = 0; cb < 4; ++cb)
#pragma unroll
      for (int i = 0; i < 4; ++i)
        Xo[(w ^ 1) * 2048 + (j * 16 + quad * 4 + i) * 64 + cb * 16 + c16] =
            o[qb][cb][i];
    if (c16 == 0)
#pragma unroll
      for (int i = 0; i < 4; ++i)
        Lo[(w ^ 1) * 32 + j * 16 + quad * 4 + i] = osum[qb][i];
  }
  __syncthreads();
  // combine own half -> Ot (bf16, A-layout-friendly [q][c] stride 72)
#pragma unroll
  for (int j = 0; j < 2; ++j) {
    const int qb = w * 2 + j;
#pragma unroll
    for (int i = 0; i < 4; ++i) {
      const float l =
          __shfl(osum[qb][i], lane & 48) + Lo[w * 32 + j * 16 + quad * 4 + i];
      const float inv = 1.0f / l;
      const int qq = qb * 16 + quad * 4 + i;
#pragma unroll
      for (int cb = 0; cb < 4; ++cb)
        Ot[qq * 72 + cb * 16 + c16] = f2bf(
            (o[qb][cb][i] +
             Xo[w * 2048 + (j * 16 + quad * 4 + i) * 64 + cb * 16 + c16]) *
            inv);
    }
  }
  __syncthreads();

  // ---- head-separable projection: atomic f32 partials into out ----
  const int b = bh >> 3, h = bh & 7;
  s16x8 aF[2][2];
#pragma unroll
  for (int j = 0; j < 2; ++j)
#pragma unroll
    for (int cc = 0; cc < 2; ++cc)
      aF[j][cc] =
          *(const s16x8*)&Ot[((w * 2 + j) * 16 + c16) * 72 + cc * 32 + quad * 8];

  f32x4 c_[2][4];
#pragma unroll
  for (int j = 0; j < 2; ++j)
#pragma unroll
    for (int nb = 0; nb < 4; ++nb) c_[j][nb] = (f32x4){0.f, 0.f, 0.f, 0.f};

#pragma unroll
  for (int cc = 0; cc < 2; ++cc)
#pragma unroll
    for (int nb = 0; nb < 4; ++nb) {
      const s16x8 wfv =
          *(const s16x8*)(WpF + ((((h * 2 + cc) * 4 + nb) << 9) + lane * 8));
#pragma unroll
      for (int j = 0; j < 2; ++j)
        c_[j][nb] = mfma_bf16(aF[j][cc], wfv, c_[j][nb]);
    }

#pragma unroll
  for (int nb = 0; nb < 4; ++nb) {
    const int col = nb * 16 + c16;
    const float badd = (h == 0) ? bias[col] : 0.0f;
#pragma unroll
    for (int j = 0; j < 2; ++j) {
      const int qbase = q0 + (w * 2 + j) * 16 + quad * 4;
#pragma unroll
      for (int i = 0; i < 4; ++i)
        atomAddF32(out + (size_t)(b * SEQ + qbase + i) * CD + col,
                   c_[j][nb][i] + badd);
    }
  }
}

// ---------------------------------------------------------------------------
extern "C" void kernel_launch(void* const* d_in, const int* in_sizes, int n_in,
                              void* d_out, int out_size, void* d_ws, size_t ws_size,
                              hipStream_t stream) {
  (void)in_sizes; (void)n_in; (void)out_size; (void)ws_size;
  const float* x     = (const float*)d_in[0];
  const float* Wqkv  = (const float*)d_in[1];
  const float* Wproj = (const float*)d_in[2];
  const float* bproj = (const float*)d_in[3];
  float* out = (float*)d_out;

  // workspace layout (u16 units), ~24.3 MB
  u16* WpF = (u16*)d_ws;                      // 64*512 fragment-packed Wproj
  u16* Qw  = WpF + CD * HC;
  u16* Kw  = Qw + (size_t)BHN * SEQ * CD;
  u16* Vtw = Kw + (size_t)BHN * SEQ * CD;     // tiled-transposed V

  qkv_kernel<<<dim3(129, 8), 256, 0, stream>>>(x, Wqkv, Wproj, Qw, Kw, Vtw,
                                               WpF);
  hipMemsetAsync(out, 0, (size_t)ROWS * CD * sizeof(float), stream);
  attnproj_kernel<<<dim3(32, 32), 128, 0, stream>>>(Qw, Kw, Vtw, WpF, bproj,
                                                    out);
}

// Round 13
// 120.758 us; speedup vs baseline: 1.1724x; 1.1724x over previous
//
#include <hip/hip_runtime.h>

// Problem constants
#define NB 4
#define SEQ 2048
#define CD 64            // head dim == model dim
#define NHEAD 8
#define BHN (NB * NHEAD) // 32
#define ROWS (NB * SEQ)  // 8192
#define HC 512           // H*CD

#define QSCALE 0.18033688011112042f   // 0.125 * log2(e)
#define SHIFT  23.083120654223414f    // 16 * log2(e)

typedef float f32x4 __attribute__((ext_vector_type(4)));
typedef short s16x8 __attribute__((ext_vector_type(8)));
typedef unsigned short u16;
typedef unsigned int u32;

__device__ __forceinline__ u16 f2bf(float x) {
  union { float f; unsigned u; } v; v.f = x;
  unsigned r = v.u + 0x7FFFu + ((v.u >> 16) & 1u);
  return (u16)(r >> 16);
}

__device__ __forceinline__ float fast_exp2(float x) {
#if __has_builtin(__builtin_amdgcn_exp2f)
  return __builtin_amdgcn_exp2f(x);
#else
  return exp2f(x);
#endif
}

__device__ __forceinline__ u32 bitsf(float x) {
  union { float f; u32 u; } v; v.f = x; return v.u;
}

// pack hi16 of two f32 (truncating bf16 convert): {lo:=a_hi16, hi:=b_hi16}
__device__ __forceinline__ u32 pack_trunc(float a, float b) {
#if __has_builtin(__builtin_amdgcn_perm)
  return __builtin_amdgcn_perm(bitsf(b), bitsf(a), 0x07060302u);
#else
  return (bitsf(a) >> 16) | (bitsf(b) & 0xFFFF0000u);
#endif
}

__device__ __forceinline__ u32 pack_rne(float a, float b) {
  return (u32)f2bf(a) | ((u32)f2bf(b) << 16);
}

__device__ __forceinline__ f32x4 mfma_bf16(s16x8 a, s16x8 b, f32x4 c) {
  return __builtin_amdgcn_mfma_f32_16x16x32_bf16(a, b, c, 0, 0, 0);
}

// ---------------------------------------------------------------------------
// Fragment-packed K/V layout:
//   per (bh, 32-key tile): 4 frags x 512 u16 (1KB). Frag elem (lane, j):
//   Kf frag fi=kb*2+cc: K[key = kb*16 + (lane&15)][c = cc*32 + (lane>>4)*8+j]
//   Vf frag cb:        V^T[c = cb*16 + (lane&15)][key = (lane>>4)*8 + j]
//   -> attn loads one frag = one coalesced global_load_dwordx4 per lane.
// ---------------------------------------------------------------------------

// ---------------------------------------------------------------------------
// Kernel 1: fused prep + qkv (R10/R11-validated core).
// blockIdx.x == 128 (8 blocks): pack Wproj into MFMA B-fragments WpF.
// blockIdx.x < 128: qkv via MFMA; Wqkv slice transposed inline into LDS.
// Q written [B,H,N,64] (row layout); K -> Kf frag-packed; V -> Vf frag-packed.
// All stores are 8B packed, each wave-store = 1KB contiguous. grid (129, 8).
// ---------------------------------------------------------------------------
__global__ void __launch_bounds__(256) qkv_kernel(
    const float* __restrict__ x, const float* __restrict__ Wqkv,
    const float* __restrict__ Wproj, u16* __restrict__ Q, u16* __restrict__ Kf,
    u16* __restrict__ Vf, u16* __restrict__ WpF) {
  const int t = threadIdx.x;

  if (blockIdx.x == 128) {
    // prep path: WpF[f*512 + lane*8 + j] = Wproj[k*64+col], f = kcg*4+nb
    for (int i = blockIdx.y * 256 + t; i < 64 * 512; i += 2048) {
      const int f = i >> 9, ln = (i >> 3) & 63, j = i & 7;
      const int col = (f & 3) * 16 + (ln & 15);
      const int k = (f >> 2) * 32 + (ln >> 4) * 8 + j;
      WpF[i] = f2bf(Wproj[k * 64 + col]);
    }
    return;
  }

  __shared__ __align__(16) u16 xs[64 * 72];    // [row][c] stride 72
  __shared__ __align__(16) u16 wts[192 * 72];  // [n][k]  stride 72

  const int w = t >> 6, lane = t & 63, quad = lane >> 4, c16 = lane & 15;
  const int rb = blockIdx.x * 64;
  const int c0 = blockIdx.y * 192;

  // stage x tile (64 rows x 64 c), f32 -> bf16, coalesced
  {
    const int row = t >> 2, cc0 = (t & 3) * 16;
    const float* xp = x + (size_t)(rb + row) * CD + cc0;
    union { u16 u[16]; int4 v[2]; } bx;
#pragma unroll
    for (int j = 0; j < 16; j += 4) {
      float4 xv = *(const float4*)(xp + j);
      bx.u[j] = f2bf(xv.x); bx.u[j + 1] = f2bf(xv.y);
      bx.u[j + 2] = f2bf(xv.z); bx.u[j + 3] = f2bf(xv.w);
    }
    *(int4*)&xs[row * 72 + cc0] = bx.v[0];
    *(int4*)&xs[row * 72 + cc0 + 8] = bx.v[1];
  }
  // stage Wqkv slice [64 k][192 n] TRANSPOSED into wts[n][k]
#pragma unroll
  for (int p = 0; p < 12; ++p) {
    const int idx = p * 256 + t;               // 0..3071 = 16 k4 x 192 n
    const int n = idx % 192, k4 = (idx / 192) * 4;
    const float* wp = Wqkv + (size_t)k4 * 1536 + c0 + n;
    const float w0 = wp[0], w1 = wp[1536], w2 = wp[3072], w3 = wp[4608];
    uint2 pk;
    pk.x = pack_rne(w0, w1);
    pk.y = pack_rne(w2, w3);
    *(uint2*)&wts[n * 72 + k4] = pk;
  }
  __syncthreads();

  s16x8 af[2];
#pragma unroll
  for (int kc = 0; kc < 2; ++kc)
    af[kc] = *(const s16x8*)&xs[(w * 16 + c16) * 72 + kc * 32 + quad * 8];

  const int rw = rb + w * 16;
  const int b = rw >> 11;
  const int nn0 = rw & (SEQ - 1);

#pragma unroll
  for (int nb = 0; nb < 12; ++nb) {
    const int cb = c0 + nb * 16;           // wave-uniform column base
    const int three = cb >> 9;
    const int h = (cb >> 6) & 7;
    const int ccb = cb & 63;
    const int bhv = b * NHEAD + h;
    s16x8 bf_[2];
#pragma unroll
    for (int kc = 0; kc < 2; ++kc)
      bf_[kc] = *(const s16x8*)&wts[(nb * 16 + c16) * 72 + kc * 32 + quad * 8];

    if (three == 2) {
      // V: un-swapped -> C[key][c]: lane c=ccb+c16, keys nn0+quad*4+{0..3}
      f32x4 acc = (f32x4){0.f, 0.f, 0.f, 0.f};
#pragma unroll
      for (int kc = 0; kc < 2; ++kc) acc = mfma_bf16(af[kc], bf_[kc], acc);
      uint2 pk;
      pk.x = pack_rne(acc[0], acc[1]);
      pk.y = pack_rne(acc[2], acc[3]);
      const int tile = nn0 >> 5;
      const int cb_ = ccb >> 4;                    // frag id 0..3
      const int kq = (nn0 & 31) + quad * 4;        // key offset in tile
      const size_t off = (size_t)bhv * (SEQ * CD) + (size_t)tile * 2048 +
                         cb_ * 512 + (kq >> 3) * 128 + c16 * 8 + (kq & 4);
      *(uint2*)(Vf + off) = pk;
    } else if (three == 1) {
      // K: swapped -> C[c][key]: lane key=nn0+c16, cols ccb+quad*4+{0..3}
      f32x4 acc = (f32x4){0.f, 0.f, 0.f, 0.f};
#pragma unroll
      for (int kc = 0; kc < 2; ++kc) acc = mfma_bf16(bf_[kc], af[kc], acc);
      uint2 pk;
      pk.x = pack_rne(acc[0], acc[1]);
      pk.y = pack_rne(acc[2], acc[3]);
      const int tile = nn0 >> 5;
      const int kb_ = (nn0 >> 4) & 1;
      const int cc_ = ccb >> 5;
      const int cq = (ccb & 31) + quad * 4;        // c offset in frag's 32-c
      const size_t off = (size_t)bhv * (SEQ * CD) + (size_t)tile * 2048 +
                         (kb_ * 2 + cc_) * 512 + (cq >> 3) * 128 + c16 * 8 +
                         (cq & 4);
      *(uint2*)(Kf + off) = pk;
    } else {
      // Q: swapped -> row layout [bh][n][c], lane row=c16, 4 cols packed
      f32x4 acc = (f32x4){0.f, 0.f, 0.f, 0.f};
#pragma unroll
      for (int kc = 0; kc < 2; ++kc) acc = mfma_bf16(bf_[kc], af[kc], acc);
      uint2 pk;
      pk.x = pack_rne(acc[0] * QSCALE, acc[1] * QSCALE);
      pk.y = pack_rne(acc[2] * QSCALE, acc[3] * QSCALE);
      *(uint2*)(Q + ((size_t)bhv * SEQ + nn0 + c16) * CD + ccb + quad * 4) = pk;
    }
  }
}

// ---------------------------------------------------------------------------
// Kernel 2: flash attention, DIRECT-GLOBAL fragment loads (no K/V LDS).
// In-block K-split x2 (wave w = keys [w*1024,(w+1)*1024)); per 32-key tile:
// 8 coalesced b128 global loads (L2-served, frag-packed layout), register
// ping-pong prefetch, per-qb P slots in LDS (only LDS use in loop).
// Fixed-shift softmax; end combine = R11-validated. grid (32,32), block 128.
// ---------------------------------------------------------------------------
__global__ void __launch_bounds__(128, 2) attn_kernel(
    const u16* __restrict__ Q, const u16* __restrict__ Kf,
    const u16* __restrict__ Vf, u16* __restrict__ O) {
  // u16 layout: K-loop: [w*2560 + qb*640]: P slot (16 x stride 40)
  //             epilogue (after barrier): X f32[64][64] @0, Lx f32[64] @8192
  __shared__ __align__(16) u16 smem[8320];

  const int t = threadIdx.x;
  const int w = t >> 6, lane = t & 63, quad = lane >> 4, c16 = lane & 15;
  const int bh = blockIdx.y;
  const int q0 = blockIdx.x * 64;

  u16* Pw = smem + w * 2560;   // 4 slots x [16*40]

  const u16* Qb = Q + (size_t)bh * SEQ * CD;
  // wave w's first tile: tile index w*32; frag pointers include lane offset
  const u16* KbT = Kf + (size_t)bh * (SEQ * CD) + (size_t)w * 32 * 2048 +
                   lane * 8;
  const u16* VbT = Vf + (size_t)bh * (SEQ * CD) + (size_t)w * 32 * 2048 +
                   lane * 8;

  // Q B-operand fragments (same for both waves): B[k=c][n=q]
  s16x8 qfb[4][2];
#pragma unroll
  for (int qb = 0; qb < 4; ++qb)
#pragma unroll
    for (int cc = 0; cc < 2; ++cc)
      qfb[qb][cc] = *(const s16x8*)(Qb + (size_t)(q0 + qb * 16 + c16) * CD +
                                    cc * 32 + quad * 8);

  s16x8 onesf;
  {
    const short one = (c16 == 0) ? (short)0x3F80 : (short)0;
#pragma unroll
    for (int j = 0; j < 8; ++j) onesf[j] = one;
  }

  f32x4 o[4][4], osum[4];
#pragma unroll
  for (int qb = 0; qb < 4; ++qb) {
    osum[qb] = (f32x4){0.f, 0.f, 0.f, 0.f};
#pragma unroll
    for (int cb = 0; cb < 4; ++cb) o[qb][cb] = (f32x4){0.f, 0.f, 0.f, 0.f};
  }

  s16x8 ka[4], va[4], kb2[4], vb2[4];

#define LOAD_TILE(kf_, vf_, it_)                                               \
  {                                                                            \
    _Pragma("unroll") for (int fi = 0; fi < 4; ++fi)                           \
        kf_[fi] = *(const s16x8*)(KbT + (it_) * 2048 + fi * 512);              \
    _Pragma("unroll") for (int cb = 0; cb < 4; ++cb)                           \
        vf_[cb] = *(const s16x8*)(VbT + (it_) * 2048 + cb * 512);              \
  }

#define COMPUTE_TILE(kf_, vf_)                                                 \
  {                                                                            \
    _Pragma("unroll") for (int qb = 0; qb < 4; ++qb) {                         \
      u16* Pq = Pw + qb * 640;                                                 \
      _Pragma("unroll") for (int kb = 0; kb < 2; ++kb) {                       \
        f32x4 s = (f32x4){-SHIFT, -SHIFT, -SHIFT, -SHIFT};                     \
        s = mfma_bf16(kf_[kb * 2], qfb[qb][0], s);                             \
        s = mfma_bf16(kf_[kb * 2 + 1], qfb[qb][1], s);                         \
        uint2 pk;                                                              \
        pk.x = pack_trunc(fast_exp2(s[0]), fast_exp2(s[1]));                   \
        pk.y = pack_trunc(fast_exp2(s[2]), fast_exp2(s[3]));                   \
        *(uint2*)&Pq[c16 * 40 + kb * 16 + quad * 4] = pk;                      \
      }                                                                        \
      const s16x8 pf = *(const s16x8*)&Pq[c16 * 40 + quad * 8];                \
      _Pragma("unroll") for (int cb = 0; cb < 4; ++cb)                         \
          o[qb][cb] = mfma_bf16(pf, vf_[cb], o[qb][cb]);                       \
      osum[qb] = mfma_bf16(pf, onesf, osum[qb]);                               \
    }                                                                          \
  }

  LOAD_TILE(ka, va, 0)
  for (int it = 0; it < 32; it += 2) {
    if (it + 1 < 32) LOAD_TILE(kb2, vb2, it + 1)
    COMPUTE_TILE(ka, va)
    if (it + 2 < 32) LOAD_TILE(ka, va, it + 2)
    if (it + 1 < 32) COMPUTE_TILE(kb2, vb2)
  }
#undef LOAD_TILE
#undef COMPUTE_TILE

  // ---- combine the two K-halves in-block (exact: fixed-shift softmax) ----
  float* X  = (float*)smem;                 // 64q x 64c f32 = 16 KB
  float* Lx = (float*)(smem + 8192);        // 64 f32

  __syncthreads();  // P slots dead; X overlays them
  if (w == 1) {
#pragma unroll
    for (int qb = 0; qb < 4; ++qb) {
#pragma unroll
      for (int cb = 0; cb < 4; ++cb)
#pragma unroll
        for (int i = 0; i < 4; ++i)
          X[(qb * 16 + quad * 4 + i) * 64 + cb * 16 + c16] = o[qb][cb][i];
      if (c16 == 0)
#pragma unroll
        for (int i = 0; i < 4; ++i)
          Lx[qb * 16 + quad * 4 + i] = osum[qb][i];
    }
  }
  __syncthreads();
  if (w == 0) {
    const int b = bh >> 3, h = bh & 7;
#pragma unroll
    for (int qb = 0; qb < 4; ++qb) {
#pragma unroll
      for (int i = 0; i < 4; ++i) {
        const float l0 = __shfl(osum[qb][i], lane & 48);
        const int qq = qb * 16 + quad * 4 + i;
        const float inv = 1.0f / (l0 + Lx[qq]);
        const int q = q0 + qq;
        u16* dst = O + ((size_t)(b * SEQ + q)) * HC + h * CD;
#pragma unroll
        for (int cb = 0; cb < 4; ++cb)
          dst[cb * 16 + c16] =
              f2bf((o[qb][cb][i] + X[qq * 64 + cb * 16 + c16]) * inv);
      }
    }
  }
}

// ---------------------------------------------------------------------------
// Kernel 3: proj via MFMA (R9/R11-validated). O bf16 [8192x512] @ WpF ->
// out f32. Block 256 = 4 waves, k-split 4 + LDS f32 reduce. grid 512.
// ---------------------------------------------------------------------------
__global__ void __launch_bounds__(256) proj_kernel(
    const u16* __restrict__ O, const u16* __restrict__ WpF,
    const float* __restrict__ bias, float* __restrict__ out) {
  __shared__ __align__(16) u16 Ls[16 * 520];       // [row][k] stride 520
  __shared__ __align__(16) float Cred[4][64][20];  // [wave][col][row+pad]
  const int t = threadIdx.x;
  const int w = t >> 6, lane = t & 63, quad = lane >> 4, c16 = lane & 15;
  const int r0 = blockIdx.x * 16;

  // preload Wp B-frags (coalesced 1KB per load)
  s16x8 wf[4][4];
#pragma unroll
  for (int kc = 0; kc < 4; ++kc)
#pragma unroll
    for (int nb = 0; nb < 4; ++nb)
      wf[kc][nb] = *(const s16x8*)(WpF + ((((w * 4 + kc) * 4 + nb) << 9) +
                                          lane * 8));

  // stage O tile coalesced: 16 lanes cover 256B of a row, 16 rows, 4 passes
  {
    const int row = t >> 4, cg = (t & 15) * 8;
#pragma unroll
    for (int p = 0; p < 4; ++p)
      *(int4*)&Ls[row * 520 + p * 128 + cg] =
          *(const int4*)(O + (size_t)(r0 + row) * HC + p * 128 + cg);
  }
  __syncthreads();

  f32x4 acc[4];
#pragma unroll
  for (int nb = 0; nb < 4; ++nb) acc[nb] = (f32x4){0.f, 0.f, 0.f, 0.f};
#pragma unroll
  for (int kc = 0; kc < 4; ++kc) {
    const s16x8 af =
        *(const s16x8*)&Ls[c16 * 520 + w * 128 + kc * 32 + quad * 8];
#pragma unroll
    for (int nb = 0; nb < 4; ++nb)
      acc[nb] = mfma_bf16(af, wf[kc][nb], acc[nb]);
  }

#pragma unroll
  for (int nb = 0; nb < 4; ++nb)
    *(f32x4*)&Cred[w][nb * 16 + c16][quad * 4] = acc[nb];
  __syncthreads();

  const int col = t & 63, rbase = (t >> 6) * 4;
  const float bv = bias[col];
#pragma unroll
  for (int j = 0; j < 4; ++j) {
    const int r = rbase + j;
    out[(size_t)(r0 + r) * CD + col] = Cred[0][col][r] + Cred[1][col][r] +
                                       Cred[2][col][r] + Cred[3][col][r] + bv;
  }
}

// ---------------------------------------------------------------------------
extern "C" void kernel_launch(void* const* d_in, const int* in_sizes, int n_in,
                              void* d_out, int out_size, void* d_ws, size_t ws_size,
                              hipStream_t stream) {
  (void)in_sizes; (void)n_in; (void)out_size; (void)ws_size;
  const float* x     = (const float*)d_in[0];
  const float* Wqkv  = (const float*)d_in[1];
  const float* Wproj = (const float*)d_in[2];
  const float* bproj = (const float*)d_in[3];
  float* out = (float*)d_out;

  // workspace layout (u16 units), ~32.3 MB
  u16* WpF = (u16*)d_ws;                      // 64*512 fragment-packed Wproj
  u16* Qw  = WpF + CD * HC;                   // row layout
  u16* Kfw = Qw + (size_t)BHN * SEQ * CD;     // fragment-packed K
  u16* Vfw = Kfw + (size_t)BHN * SEQ * CD;    // fragment-packed V^T
  u16* Ow  = Vfw + (size_t)BHN * SEQ * CD;    // O bf16 [B,N,HC]

  qkv_kernel<<<dim3(129, 8), 256, 0, stream>>>(x, Wqkv, Wproj, Qw, Kfw, Vfw,
                                               WpF);
  attn_kernel<<<dim3(32, 32), 128, 0, stream>>>(Qw, Kfw, Vfw, Ow);
  proj_kernel<<<512, 256, 0, stream>>>(Ow, WpF, bproj, out);
}